// Round 6
// baseline (1844.027 us; speedup 1.0000x reference)
//
#include <hip/hip_runtime.h>
#include <math.h>

// Problem dims
constexpr int Bb  = 4;
constexpr int Ls  = 2048;
constexpr int DM  = 256;   // d_model
constexpr int DI  = 512;   // d_inner
constexpr int DSt = 16;    // d_state
constexpr int DRk = 16;    // dt_rank
constexpr int NL  = 4;
constexpr int DIN = 64;
constexpr int M   = Bb * Ls;   // 8192 tokens

#define NCH 128  // scan chunks
#define CLN 16   // chunk length (NCH*CLN == Ls)

using f32x4  = __attribute__((ext_vector_type(4))) float;
using bf16x8 = __attribute__((ext_vector_type(8))) __bf16;

__device__ __forceinline__ float silu_f(float x) { return x / (1.f + __expf(-x)); }
__device__ __forceinline__ float softplus_f(float x) {
  return fmaxf(x, 0.f) + log1pf(__expf(-fabsf(x)));
}
__device__ __forceinline__ unsigned short f2bf(float x) {
  union { float f; unsigned u; } v; v.f = x;
  unsigned r = v.u + 0x7fff + ((v.u >> 16) & 1);
  return (unsigned short)(r >> 16);
}
__device__ __forceinline__ float bf2f(unsigned short v) {
  union { unsigned u; float f; } x; x.u = ((unsigned)v) << 16; return x.f;
}
// async global->LDS 16B/lane; LDS dest = wave-uniform base + lane*16
__device__ __forceinline__ void gl_lds16(const unsigned short* g, unsigned short* l) {
  __builtin_amdgcn_global_load_lds(
      (const __attribute__((address_space(1))) unsigned int*)(const void*)g,
      (__attribute__((address_space(3))) unsigned int*)(void*)l, 16, 0, 0);
}

// ---------------------------------------------------------------------------
// One-shot weight prep: transposes (fp32) + bf16 casts, single kernel.
// ---------------------------------------------------------------------------
__global__ __launch_bounds__(256) void prep_kernel(
    const float* __restrict__ ipw, const float* __restrict__ xpw,
    const float* __restrict__ dtw, const float* __restrict__ inw,
    const float* __restrict__ outw, const float* __restrict__ opw,
    float* __restrict__ ipw_t, unsigned short* __restrict__ xpwb,
    float* __restrict__ dtw_t, unsigned short* __restrict__ inwb,
    unsigned short* __restrict__ outwb, unsigned short* __restrict__ opwb) {
  int i = blockIdx.x * 256 + threadIdx.x;
  const int S0 = 16384, S1 = 98304, S2 = 32768, S3 = 1048576, S4 = 524288, S5 = 65536;
  if (i < S0) { int k = i >> 8, n = i & 255; ipw_t[i] = ipw[n * 64 + k]; return; }
  i -= S0;
  if (i < S1) { xpwb[i] = f2bf(xpw[i]); return; }  // [l][48][512] stays N-major
  i -= S1;
  if (i < S2) {
    int l = i >> 13, rr = i & 8191, r = rr >> 9, d = rr & 511;
    dtw_t[i] = dtw[l * 8192 + d * 16 + r]; return;  // -> [l][r][d]
  }
  i -= S2;
  if (i < S3) { inwb[i] = f2bf(inw[i]); return; }
  i -= S3;
  if (i < S4) { outwb[i] = f2bf(outw[i]); return; }
  i -= S4;
  if (i < S5) { opwb[i] = f2bf(opw[i]); }
}

// ---------------------------------------------------------------------------
// fp32 matmul for in_proj (K=64): C = A[M,K] * Wt[K,N] + bias; + bf16 shadow.
// ---------------------------------------------------------------------------
template <int K, int N, int TM, int PT>
__global__ __launch_bounds__(256) void matmul_tm(
    const float* __restrict__ A, int lda,
    const float* __restrict__ Wt, const float* __restrict__ bias,
    float* __restrict__ C, unsigned short* __restrict__ Cb) {
  __shared__ float As[TM][K];
  const int m0 = blockIdx.x * TM;
  const int t = threadIdx.x;
  for (int i = t; i < TM * K; i += 256) {
    int mm = i / K, kk = i % K;
    As[mm][kk] = A[(size_t)(m0 + mm) * lda + kk];
  }
  __syncthreads();
  float acc[TM][PT];
#pragma unroll
  for (int mm = 0; mm < TM; mm++)
#pragma unroll
    for (int p = 0; p < PT; p++) acc[mm][p] = 0.f;
  for (int k = 0; k < K; k++) {
    float w[PT];
#pragma unroll
    for (int p = 0; p < PT; p++) w[p] = Wt[(size_t)k * N + p * 256 + t];
#pragma unroll
    for (int mm = 0; mm < TM; mm++) {
      float a = As[mm][k];
#pragma unroll
      for (int p = 0; p < PT; p++) acc[mm][p] = fmaf(a, w[p], acc[mm][p]);
    }
  }
#pragma unroll
  for (int mm = 0; mm < TM; mm++) {
#pragma unroll
    for (int p = 0; p < PT; p++) {
      int n = p * 256 + t;
      float v = acc[mm][p] + bias[n];
      C[(size_t)(m0 + mm) * N + n] = v;
      Cb[(size_t)(m0 + mm) * N + n] = f2bf(v);
    }
  }
}

// ---------------------------------------------------------------------------
// bf16 MFMA GEMM, m97-style staging. W is [Ntot][K] row-major (= B^T).
// MODE 1: C[gr*Ntot+gc] = v + extra[gc]  (bias)
// MODE 3: split: gc<DI -> C (fp32, stride DI), else Cb bf16 (stride DI)
// ---------------------------------------------------------------------------
template <int K, int Ntot, int BM, int BN, int MODE>
__global__ __launch_bounds__(256) void gemm_bf16(
    const unsigned short* __restrict__ A,
    const unsigned short* __restrict__ W,
    const float* __restrict__ extra,
    float* __restrict__ C, unsigned short* __restrict__ Cb) {
  constexpr int WM = BM / 2, WN = BN / 2, MI = WM / 16, NI = WN / 16;
  constexpr int CH = (BM + BN) / 16;
  __shared__ __align__(16) unsigned short S[(BM + BN) * 32];
  const int t = threadIdx.x;
  const int m0 = blockIdx.x * BM, n0 = blockIdx.y * BN;
  const int wave = t >> 6, lane = t & 63;
  const int wm = wave & 1, wn = wave >> 1;
  const int lm = lane & 15, quad = lane >> 4;
  const int lrow = lane >> 2, lcol = (lane & 3) * 8;

  f32x4 acc[MI][NI];
#pragma unroll
  for (int i = 0; i < MI; i++)
#pragma unroll
    for (int j = 0; j < NI; j++) acc[i][j] = (f32x4){0.f, 0.f, 0.f, 0.f};

  for (int k0 = 0; k0 < K; k0 += 32) {
    if (k0) __syncthreads();
    for (int c = wave; c < CH; c += 4) {
      int row0 = c * 16;
      const unsigned short* src =
          (row0 < BM) ? A + (size_t)(m0 + row0 + lrow) * K + k0 + lcol
                      : W + (size_t)(n0 + row0 - BM + lrow) * K + k0 + lcol;
      gl_lds16(src, &S[row0 * 32]);
    }
    __syncthreads();
    bf16x8 af[MI], bfr[NI];
#pragma unroll
    for (int i = 0; i < MI; i++)
      af[i] = *(const bf16x8*)&S[(wm * WM + i * 16 + lm) * 32 + quad * 8];
#pragma unroll
    for (int j = 0; j < NI; j++)
      bfr[j] = *(const bf16x8*)&S[(BM + wn * WN + j * 16 + lm) * 32 + quad * 8];
#pragma unroll
    for (int i = 0; i < MI; i++)
#pragma unroll
      for (int j = 0; j < NI; j++)
        acc[i][j] = __builtin_amdgcn_mfma_f32_16x16x32_bf16(
            af[i], bfr[j], acc[i][j], 0, 0, 0);
  }
#pragma unroll
  for (int i = 0; i < MI; i++)
#pragma unroll
    for (int j = 0; j < NI; j++)
#pragma unroll
      for (int r = 0; r < 4; r++) {
        int gr = m0 + wm * WM + i * 16 + quad * 4 + r;
        int gc = n0 + wn * WN + j * 16 + lm;
        float v = acc[i][j][r];
        if constexpr (MODE == 1) {
          C[(size_t)gr * Ntot + gc] = v + extra[gc];
        } else {  // MODE 3
          if (gc < DI) C[(size_t)gr * DI + gc] = v;
          else Cb[(size_t)gr * DI + gc - DI] = f2bf(v);
        }
      }
}

// ---------------------------------------------------------------------------
// outw GEMM (K=512, N=256) + residual + LayerNorm fused. BM=32, BN=256.
// ---------------------------------------------------------------------------
__global__ __launch_bounds__(256) void gemm_outw_ln(
    const unsigned short* __restrict__ A,   // gbf [M][512]
    const unsigned short* __restrict__ W,   // outwb_l [256][512]
    const float* __restrict__ lnw_l, const float* __restrict__ lnb_l,
    float* __restrict__ h, unsigned short* __restrict__ hb) {
  constexpr int BM = 32, BN = 256, K = 512, NI = 8, CH = (BM + BN) / 16;
  __shared__ __align__(16) unsigned short S[(BM + BN) * 32];
  __shared__ float redS[2][2][16], redQ[2][2][16];
  const int t = threadIdx.x;
  const int m0 = blockIdx.x * BM;
  const int wave = t >> 6, lane = t & 63;
  const int wm = wave & 1, wn = wave >> 1;
  const int lm = lane & 15, quad = lane >> 4;
  const int lrow = lane >> 2, lcol = (lane & 3) * 8;

  f32x4 acc[NI];
#pragma unroll
  for (int j = 0; j < NI; j++) acc[j] = (f32x4){0.f, 0.f, 0.f, 0.f};

  for (int k0 = 0; k0 < K; k0 += 32) {
    if (k0) __syncthreads();
    for (int c = wave; c < CH; c += 4) {
      int row0 = c * 16;
      const unsigned short* src =
          (row0 < BM) ? A + (size_t)(m0 + row0 + lrow) * K + k0 + lcol
                      : W + (size_t)(row0 - BM + lrow) * K + k0 + lcol;
      gl_lds16(src, &S[row0 * 32]);
    }
    __syncthreads();
    bf16x8 af = *(const bf16x8*)&S[(wm * 16 + lm) * 32 + quad * 8];
#pragma unroll
    for (int j = 0; j < NI; j++) {
      bf16x8 bfr = *(const bf16x8*)&S[(BM + wn * 128 + j * 16 + lm) * 32 + quad * 8];
      acc[j] = __builtin_amdgcn_mfma_f32_16x16x32_bf16(af, bfr, acc[j], 0, 0, 0);
    }
  }

  float vv[NI][4];
#pragma unroll
  for (int j = 0; j < NI; j++)
#pragma unroll
    for (int r = 0; r < 4; r++) {
      int gr = m0 + wm * 16 + quad * 4 + r;
      int gc = wn * 128 + j * 16 + lm;
      vv[j][r] = acc[j][r] + h[(size_t)gr * DM + gc];
    }
  float s1[4], s2[4];
#pragma unroll
  for (int r = 0; r < 4; r++) {
    float a = 0.f, b = 0.f;
#pragma unroll
    for (int j = 0; j < NI; j++) { a += vv[j][r]; b += vv[j][r] * vv[j][r]; }
    s1[r] = a; s2[r] = b;
  }
#pragma unroll
  for (int off = 1; off < 16; off <<= 1) {
#pragma unroll
    for (int r = 0; r < 4; r++) {
      s1[r] += __shfl_xor(s1[r], off, 64);
      s2[r] += __shfl_xor(s2[r], off, 64);
    }
  }
  if (lm == 0) {
#pragma unroll
    for (int r = 0; r < 4; r++) {
      redS[wm][wn][quad * 4 + r] = s1[r];
      redQ[wm][wn][quad * 4 + r] = s2[r];
    }
  }
  __syncthreads();
#pragma unroll
  for (int r = 0; r < 4; r++) {
    int row16 = quad * 4 + r;
    int gr = m0 + wm * 16 + row16;
    float mu  = (redS[wm][0][row16] + redS[wm][1][row16]) * (1.f / 256.f);
    float msq = (redQ[wm][0][row16] + redQ[wm][1][row16]) * (1.f / 256.f);
    float inv = rsqrtf(msq - mu * mu + 1e-5f);
#pragma unroll
    for (int j = 0; j < NI; j++) {
      int gc = wn * 128 + j * 16 + lm;
      float o = (vv[j][r] - mu) * inv * lnw_l[gc] + lnb_l[gc];
      h[(size_t)gr * DM + gc] = o;
      hb[(size_t)gr * DM + gc] = f2bf(o);
    }
  }
}

// ---------------------------------------------------------------------------
// Elementwise causal conv(k=4)+SiLU. float4 over d.
// Writes uc_t (fp32, TRANSPOSED [d][tok]) + ucb (bf16, row-major).
// ---------------------------------------------------------------------------
__global__ __launch_bounds__(256) void conv_silu_kernel(
    const float* __restrict__ u_g, const float* __restrict__ convw_l,
    const float* __restrict__ convb_l, float* __restrict__ uc_t,
    unsigned short* __restrict__ ucb) {
  int idx = blockIdx.x * 256 + threadIdx.x;   // M * DI/4 = 1,048,576
  int d4 = idx & 127;            // group of 4 d
  int tok = idx >> 7;            // 0..8191
  int l = tok & (Ls - 1);
  float4 u4[4];
#pragma unroll
  for (int k = 0; k < 4; k++) {
    int ls = l - 3 + k;
    u4[k] = (ls >= 0) ? *(const float4*)(u_g + (size_t)(tok - 3 + k) * DI + d4 * 4)
                      : make_float4(0.f, 0.f, 0.f, 0.f);
  }
  const float4* wrow = (const float4*)(convw_l + d4 * 16);  // [4 d][4 k]
  float4 w0 = wrow[0], w1 = wrow[1], w2 = wrow[2], w3 = wrow[3];
  float4 bz = *(const float4*)(convb_l + d4 * 4);
  float4 r;
  r.x = bz.x + u4[0].x * w0.x + u4[1].x * w0.y + u4[2].x * w0.z + u4[3].x * w0.w;
  r.y = bz.y + u4[0].y * w1.x + u4[1].y * w1.y + u4[2].y * w1.z + u4[3].y * w1.w;
  r.z = bz.z + u4[0].z * w2.x + u4[1].z * w2.y + u4[2].z * w2.z + u4[3].z * w2.w;
  r.w = bz.w + u4[0].w * w3.x + u4[1].w * w3.y + u4[2].w * w3.z + u4[3].w * w3.w;
  r.x = silu_f(r.x); r.y = silu_f(r.y); r.z = silu_f(r.z); r.w = silu_f(r.w);
  uc_t[(size_t)(d4 * 4 + 0) * M + tok] = r.x;
  uc_t[(size_t)(d4 * 4 + 1) * M + tok] = r.y;
  uc_t[(size_t)(d4 * 4 + 2) * M + tok] = r.z;
  uc_t[(size_t)(d4 * 4 + 3) * M + tok] = r.w;
  ushort4 rb;
  rb.x = f2bf(r.x); rb.y = f2bf(r.y); rb.z = f2bf(r.z); rb.w = f2bf(r.w);
  *(ushort4*)(ucb + (size_t)tok * DI + d4 * 4) = rb;
}

// ---------------------------------------------------------------------------
// Fused: dbc = ucb @ xpwb^T (MFMA) with dt kept in LDS; B,C -> transposed
// Bt/Ct [16][M]; then delta = softplus(dt @ dtw^T + dtb) -> dlt_t [512][M].
// Block = 64 tokens, grid 128.
// ---------------------------------------------------------------------------
__global__ __launch_bounds__(256) void gemm_dbc_delta(
    const unsigned short* __restrict__ A, const unsigned short* __restrict__ W,
    const float* __restrict__ dtw_tl, const float* __restrict__ dtb_l,
    float* __restrict__ Bt, float* __restrict__ Ct,
    float* __restrict__ dlt_t) {
  constexpr int K = 512;
  __shared__ __align__(16) unsigned short S[(64 + 48) * 32];
  __shared__ __align__(16) float dts[64][20];   // pad 20: 2-way conflict (free)
  const int t = threadIdx.x;
  const int m0 = blockIdx.x * 64;
  const int wave = t >> 6, lane = t & 63;
  const int lm = lane & 15, quad = lane >> 4;
  const int lrow = lane >> 2, lcol = (lane & 3) * 8;

  f32x4 acc[3];
#pragma unroll
  for (int j = 0; j < 3; j++) acc[j] = (f32x4){0.f, 0.f, 0.f, 0.f};

  for (int k0 = 0; k0 < K; k0 += 32) {
    if (k0) __syncthreads();
    for (int c = wave; c < 7; c += 4) {
      int row0 = c * 16;
      const unsigned short* src =
          (row0 < 64) ? A + (size_t)(m0 + row0 + lrow) * K + k0 + lcol
                      : W + (size_t)(row0 - 64 + lrow) * K + k0 + lcol;
      gl_lds16(src, &S[row0 * 32]);
    }
    __syncthreads();
    bf16x8 af = *(const bf16x8*)&S[(wave * 16 + lm) * 32 + quad * 8];
#pragma unroll
    for (int j = 0; j < 3; j++) {
      bf16x8 bfr = *(const bf16x8*)&S[(64 + j * 16 + lm) * 32 + quad * 8];
      acc[j] = __builtin_amdgcn_mfma_f32_16x16x32_bf16(af, bfr, acc[j], 0, 0, 0);
    }
  }
  // j=0 -> dt to LDS; j=1 -> Bt[s][tok]; j=2 -> Ct[s][tok]
#pragma unroll
  for (int r = 0; r < 4; r++) {
    int rowl = wave * 16 + quad * 4 + r;
    dts[rowl][lm] = acc[0][r];
    Bt[(size_t)lm * M + m0 + rowl] = acc[1][r];
    Ct[(size_t)lm * M + m0 + rowl] = acc[2][r];
  }
  __syncthreads();

  // delta phase: thread -> (d4 = t&127, half = t>>7), 32 rows each
  int d4 = t & 127, half = t >> 7;
  f32x4 wv[16];
#pragma unroll
  for (int r = 0; r < 16; r++) wv[r] = *(const f32x4*)(dtw_tl + r * DI + d4 * 4);
  f32x4 bz = *(const f32x4*)(dtb_l + d4 * 4);
  for (int rl = 0; rl < 32; rl++) {
    int rowl = half * 32 + rl;
    f32x4 accd = bz;
#pragma unroll
    for (int r4 = 0; r4 < 4; r4++) {
      f32x4 dtq = *(const f32x4*)&dts[rowl][r4 * 4];
#pragma unroll
      for (int e2 = 0; e2 < 4; e2++) {
        float dtv = dtq[e2];
        f32x4 w = wv[r4 * 4 + e2];
#pragma unroll
        for (int e = 0; e < 4; e++) accd[e] = fmaf(dtv, w[e], accd[e]);
      }
    }
    int tok = m0 + rowl;
#pragma unroll
    for (int e = 0; e < 4; e++)
      dlt_t[(size_t)(d4 * 4 + e) * M + tok] = softplus_f(accd[e]);
  }
}

// ---------------------------------------------------------------------------
// Single-kernel chunked scan: block = (b, d), thread = chunk.
// Phase 1: local scan (P, h) per chunk. Phase 2: in-LDS affine Hillis-Steele
// prefix over 128 chunks. Phase 3: replay from exclusive prefix, emit
// g = y*silu(z) -> gbf (row-major, for outw GEMM).
// ---------------------------------------------------------------------------
__global__ __launch_bounds__(128, 3) void scan_fused(
    const float* __restrict__ dlt_t, const float* __restrict__ uc_t,
    const float* __restrict__ Bt, const float* __restrict__ Ct,
    const float* __restrict__ a_log_l, const float* __restrict__ dparam_l,
    const unsigned short* __restrict__ zb, unsigned short* __restrict__ gbf) {
  __shared__ float Ps[DSt][NCH];
  __shared__ float Hs[DSt][NCH];
  const int d = blockIdx.x & (DI - 1);
  const int b = blockIdx.x >> 9;
  const int c = threadIdx.x;
  const int tok0 = b * Ls + c * CLN;

  float Aa[DSt];
#pragma unroll
  for (int s = 0; s < DSt; s++) Aa[s] = -__expf(a_log_l[d * DSt + s]);
  float p[DSt], h[DSt];
#pragma unroll
  for (int s = 0; s < DSt; s++) { p[s] = 1.f; h[s] = 0.f; }

  const float* dltp = dlt_t + (size_t)d * M + tok0;
  const float* ucp  = uc_t  + (size_t)d * M + tok0;

  // phase 1: local chunk scan
#pragma unroll
  for (int g = 0; g < CLN / 4; g++) {
    f32x4 dlt4 = *(const f32x4*)(dltp + g * 4);
    f32x4 u4   = *(const f32x4*)(ucp + g * 4);
    f32x4 du4;
#pragma unroll
    for (int e = 0; e < 4; e++) du4[e] = dlt4[e] * u4[e];
#pragma unroll
    for (int s = 0; s < DSt; s++) {
      f32x4 B4 = *(const f32x4*)(Bt + (size_t)s * M + tok0 + g * 4);
#pragma unroll
      for (int e = 0; e < 4; e++) {
        float dA = __expf(dlt4[e] * Aa[s]);
        p[s] *= dA;
        h[s] = fmaf(dA, h[s], du4[e] * B4[e]);
      }
    }
  }

  // phase 2: Hillis-Steele affine prefix scan over chunks
#pragma unroll
  for (int s = 0; s < DSt; s++) { Ps[s][c] = p[s]; Hs[s][c] = h[s]; }
  __syncthreads();
  for (int step = 1; step < NCH; step <<= 1) {
    float pp[DSt], hh[DSt];
    if (c >= step) {
#pragma unroll
      for (int s = 0; s < DSt; s++) { pp[s] = Ps[s][c - step]; hh[s] = Hs[s][c - step]; }
    } else {
#pragma unroll
      for (int s = 0; s < DSt; s++) { pp[s] = 1.f; hh[s] = 0.f; }
    }
    __syncthreads();
#pragma unroll
    for (int s = 0; s < DSt; s++) {
      h[s] = fmaf(p[s], hh[s], h[s]);
      p[s] *= pp[s];
      Ps[s][c] = p[s]; Hs[s][c] = h[s];
    }
    __syncthreads();
  }
  // exclusive prefix = chunk entry state
#pragma unroll
  for (int s = 0; s < DSt; s++) h[s] = (c > 0) ? Hs[s][c - 1] : 0.f;

  // phase 3: replay
  float Dp = dparam_l[d];
#pragma unroll
  for (int g = 0; g < CLN / 4; g++) {
    f32x4 dlt4 = *(const f32x4*)(dltp + g * 4);
    f32x4 u4   = *(const f32x4*)(ucp + g * 4);
    f32x4 du4;
#pragma unroll
    for (int e = 0; e < 4; e++) du4[e] = dlt4[e] * u4[e];
    f32x4 y4 = (f32x4){0.f, 0.f, 0.f, 0.f};
#pragma unroll
    for (int s = 0; s < DSt; s++) {
      f32x4 B4 = *(const f32x4*)(Bt + (size_t)s * M + tok0 + g * 4);
      f32x4 C4 = *(const f32x4*)(Ct + (size_t)s * M + tok0 + g * 4);
#pragma unroll
      for (int e = 0; e < 4; e++) {
        float dA = __expf(dlt4[e] * Aa[s]);
        h[s] = fmaf(dA, h[s], du4[e] * B4[e]);
        y4[e] = fmaf(h[s], C4[e], y4[e]);
      }
    }
#pragma unroll
    for (int e = 0; e < 4; e++) {
      int tok = tok0 + g * 4 + e;
      float y = fmaf(u4[e], Dp, y4[e]);
      float z = bf2f(zb[(size_t)tok * DI + d]);
      gbf[(size_t)tok * DI + d] = f2bf(y * silu_f(z));
    }
  }
}

// ---------------------------------------------------------------------------
extern "C" void kernel_launch(void* const* d_in, const int* in_sizes, int n_in,
                              void* d_out, int out_size, void* d_ws,
                              size_t ws_size, hipStream_t stream) {
  const float* x      = (const float*)d_in[0];
  const float* ipw    = (const float*)d_in[1];
  const float* ipb    = (const float*)d_in[2];
  const float* opw    = (const float*)d_in[3];
  const float* opb    = (const float*)d_in[4];
  const float* inw    = (const float*)d_in[5];
  const float* convw  = (const float*)d_in[6];
  const float* convb  = (const float*)d_in[7];
  const float* xpw    = (const float*)d_in[8];
  const float* dtw    = (const float*)d_in[9];
  const float* dtb    = (const float*)d_in[10];
  const float* a_log  = (const float*)d_in[11];
  const float* dparam = (const float*)d_in[12];
  const float* outw   = (const float*)d_in[13];
  const float* lnw    = (const float*)d_in[14];
  const float* lnb    = (const float*)d_in[15];
  float* out = (float*)d_out;

  float* ws = (float*)d_ws;
  size_t o = 0;
  float* h     = ws + o; o += (size_t)M * DM;
  float* u_g   = ws + o; o += (size_t)M * DI;
  float* uc_t  = ws + o; o += (size_t)M * DI;
  float* dlt_t = ws + o; o += (size_t)M * DI;
  float* Btb   = ws + o; o += (size_t)DSt * M;
  float* Ctb   = ws + o; o += (size_t)DSt * M;
  float* ipw_t = ws + o; o += (size_t)DIN * DM;
  float* dtw_t = ws + o; o += (size_t)NL * DRk * DI;
  unsigned short* hb    = (unsigned short*)(ws + o); o += (size_t)M * DM / 2;
  unsigned short* zb    = (unsigned short*)(ws + o); o += (size_t)M * DI / 2;
  unsigned short* gbf   = (unsigned short*)(ws + o); o += (size_t)M * DI / 2;
  unsigned short* ucb   = (unsigned short*)(ws + o); o += (size_t)M * DI / 2;
  unsigned short* inwb  = (unsigned short*)(ws + o); o += (size_t)NL * 2 * DI * DM / 2;
  unsigned short* outwb = (unsigned short*)(ws + o); o += (size_t)NL * DM * DI / 2;
  unsigned short* opwb  = (unsigned short*)(ws + o); o += (size_t)DM * DM / 2;
  unsigned short* xpwb  = (unsigned short*)(ws + o); o += (size_t)NL * 48 * DI / 2;
  (void)ws_size; (void)in_sizes; (void)n_in; (void)out_size;

  prep_kernel<<<dim3(6976), dim3(256), 0, stream>>>(
      ipw, xpw, dtw, inw, outw, opw, ipw_t, xpwb, dtw_t, inwb, outwb, opwb);

  // in_proj: x(8192x64) @ ipw_t + b -> h fp32 + hb bf16
  matmul_tm<DIN, DM, 16, 1><<<dim3(M / 16), dim3(256), 0, stream>>>(
      x, DIN, ipw_t, ipb, h, hb);

  for (int l = 0; l < NL; l++) {
    const unsigned short* inwb_l  = inwb  + (size_t)l * 2 * DI * DM;
    const unsigned short* outwb_l = outwb + (size_t)l * DM * DI;
    const unsigned short* xpwb_l  = xpwb  + (size_t)l * 48 * DI;
    const float* dtw_tl  = dtw_t + (size_t)l * DRk * DI;
    const float* a_log_l = a_log + (size_t)l * DI * DSt;
    const float* dtb_l   = dtb + (size_t)l * DI;

    // xz = h @ inw^T: u half -> fp32, z half -> bf16
    gemm_bf16<DM, 2 * DI, 128, 128, 3>
        <<<dim3(M / 128, (2 * DI) / 128), dim3(256), 0, stream>>>(
            hb, inwb_l, nullptr, u_g, zb);
    // conv + silu -> uc_t (transposed) + ucb
    conv_silu_kernel<<<dim3(M * DI / 4 / 256), dim3(256), 0, stream>>>(
        u_g, convw + (size_t)l * DI * 4, convb + (size_t)l * DI, uc_t, ucb);
    // dbc MFMA + delta (fused) -> Bt/Ct/dlt_t (all transposed)
    gemm_dbc_delta<<<dim3(M / 64), dim3(256), 0, stream>>>(
        ucb, xpwb_l, dtw_tl, dtb_l, Btb, Ctb, dlt_t);
    // single-kernel chunked scan
    scan_fused<<<dim3(Bb * DI), dim3(NCH), 0, stream>>>(
        dlt_t, uc_t, Btb, Ctb, a_log_l, dparam + (size_t)l * DI, zb, gbf);
    // outw GEMM + residual + LayerNorm -> h fp32 + hb bf16
    gemm_outw_ln<<<dim3(M / 32), dim3(256), 0, stream>>>(
        gbf, outwb_l, lnw + (size_t)l * DM, lnb + (size_t)l * DM, h, hb);
  }

  // final projection: hb @ opw^T + b -> out
  gemm_bf16<DM, DM, 64, 128, 1>
      <<<dim3(M / 64, DM / 128), dim3(256), 0, stream>>>(
          hb, opwb, opb, out, nullptr);
}

// Round 7
// 612.114 us; speedup vs baseline: 3.0126x; 3.0126x over previous
//
#include <hip/hip_runtime.h>
#include <math.h>

// Problem dims
constexpr int Bb  = 4;
constexpr int Ls  = 2048;
constexpr int DM  = 256;   // d_model
constexpr int DI  = 512;   // d_inner
constexpr int DSt = 16;    // d_state
constexpr int DRk = 16;    // dt_rank
constexpr int NL  = 4;
constexpr int DIN = 64;
constexpr int M   = Bb * Ls;   // 8192 tokens

#define NCH 128  // scan chunks
#define CLN 16   // chunk length (NCH*CLN == Ls)

using f32x4  = __attribute__((ext_vector_type(4))) float;
using bf16x8 = __attribute__((ext_vector_type(8))) __bf16;

__device__ __forceinline__ float silu_f(float x) { return x / (1.f + __expf(-x)); }
__device__ __forceinline__ float softplus_f(float x) {
  return fmaxf(x, 0.f) + log1pf(__expf(-fabsf(x)));
}
__device__ __forceinline__ unsigned short f2bf(float x) {
  union { float f; unsigned u; } v; v.f = x;
  unsigned r = v.u + 0x7fff + ((v.u >> 16) & 1);
  return (unsigned short)(r >> 16);
}
__device__ __forceinline__ float bf2f(unsigned short v) {
  union { unsigned u; float f; } x; x.u = ((unsigned)v) << 16; return x.f;
}
// async global->LDS 16B/lane; LDS dest = wave-uniform base + lane*16
__device__ __forceinline__ void gl_lds16(const unsigned short* g, unsigned short* l) {
  __builtin_amdgcn_global_load_lds(
      (const __attribute__((address_space(1))) unsigned int*)(const void*)g,
      (__attribute__((address_space(3))) unsigned int*)(void*)l, 16, 0, 0);
}

// ---------------------------------------------------------------------------
// One-shot weight prep: transposes (fp32) + bf16 casts, single kernel.
// ---------------------------------------------------------------------------
__global__ __launch_bounds__(256) void prep_kernel(
    const float* __restrict__ ipw, const float* __restrict__ xpw,
    const float* __restrict__ dtw, const float* __restrict__ inw,
    const float* __restrict__ outw, const float* __restrict__ opw,
    float* __restrict__ ipw_t, unsigned short* __restrict__ xpwb,
    float* __restrict__ dtw_t, unsigned short* __restrict__ inwb,
    unsigned short* __restrict__ outwb, unsigned short* __restrict__ opwb) {
  int i = blockIdx.x * 256 + threadIdx.x;
  const int S0 = 16384, S1 = 98304, S2 = 32768, S3 = 1048576, S4 = 524288, S5 = 65536;
  if (i < S0) { int k = i >> 8, n = i & 255; ipw_t[i] = ipw[n * 64 + k]; return; }
  i -= S0;
  if (i < S1) { xpwb[i] = f2bf(xpw[i]); return; }  // [l][48][512] stays N-major
  i -= S1;
  if (i < S2) {
    int l = i >> 13, rr = i & 8191, r = rr >> 9, d = rr & 511;
    dtw_t[i] = dtw[l * 8192 + d * 16 + r]; return;  // -> [l][r][d]
  }
  i -= S2;
  if (i < S3) { inwb[i] = f2bf(inw[i]); return; }
  i -= S3;
  if (i < S4) { outwb[i] = f2bf(outw[i]); return; }
  i -= S4;
  if (i < S5) { opwb[i] = f2bf(opw[i]); }
}

// ---------------------------------------------------------------------------
// fp32 matmul for in_proj (K=64): C = A[M,K] * Wt[K,N] + bias; + bf16 shadow.
// ---------------------------------------------------------------------------
template <int K, int N, int TM, int PT>
__global__ __launch_bounds__(256) void matmul_tm(
    const float* __restrict__ A, int lda,
    const float* __restrict__ Wt, const float* __restrict__ bias,
    float* __restrict__ C, unsigned short* __restrict__ Cb) {
  __shared__ float As[TM][K];
  const int m0 = blockIdx.x * TM;
  const int t = threadIdx.x;
  for (int i = t; i < TM * K; i += 256) {
    int mm = i / K, kk = i % K;
    As[mm][kk] = A[(size_t)(m0 + mm) * lda + kk];
  }
  __syncthreads();
  float acc[TM][PT];
#pragma unroll
  for (int mm = 0; mm < TM; mm++)
#pragma unroll
    for (int p = 0; p < PT; p++) acc[mm][p] = 0.f;
  for (int k = 0; k < K; k++) {
    float w[PT];
#pragma unroll
    for (int p = 0; p < PT; p++) w[p] = Wt[(size_t)k * N + p * 256 + t];
#pragma unroll
    for (int mm = 0; mm < TM; mm++) {
      float a = As[mm][k];
#pragma unroll
      for (int p = 0; p < PT; p++) acc[mm][p] = fmaf(a, w[p], acc[mm][p]);
    }
  }
#pragma unroll
  for (int mm = 0; mm < TM; mm++) {
#pragma unroll
    for (int p = 0; p < PT; p++) {
      int n = p * 256 + t;
      float v = acc[mm][p] + bias[n];
      C[(size_t)(m0 + mm) * N + n] = v;
      Cb[(size_t)(m0 + mm) * N + n] = f2bf(v);
    }
  }
}

// ---------------------------------------------------------------------------
// bf16 MFMA GEMM, m97-style staging. W is [Ntot][K] row-major (= B^T).
// MODE 1: C[gr*Ntot+gc] = v + extra[gc]  (bias, fp32 out)
// MODE 3: split bf16: gc<DI -> Cb (u), else Cb2 (z); both stride DI
// ---------------------------------------------------------------------------
template <int K, int Ntot, int BM, int BN, int MODE>
__global__ __launch_bounds__(256) void gemm_bf16(
    const unsigned short* __restrict__ A,
    const unsigned short* __restrict__ W,
    const float* __restrict__ extra,
    float* __restrict__ C, unsigned short* __restrict__ Cb,
    unsigned short* __restrict__ Cb2) {
  constexpr int WM = BM / 2, WN = BN / 2, MI = WM / 16, NI = WN / 16;
  constexpr int CH = (BM + BN) / 16;
  __shared__ __align__(16) unsigned short S[(BM + BN) * 32];
  const int t = threadIdx.x;
  const int m0 = blockIdx.x * BM, n0 = blockIdx.y * BN;
  const int wave = t >> 6, lane = t & 63;
  const int wm = wave & 1, wn = wave >> 1;
  const int lm = lane & 15, quad = lane >> 4;
  const int lrow = lane >> 2, lcol = (lane & 3) * 8;

  f32x4 acc[MI][NI];
#pragma unroll
  for (int i = 0; i < MI; i++)
#pragma unroll
    for (int j = 0; j < NI; j++) acc[i][j] = (f32x4){0.f, 0.f, 0.f, 0.f};

  for (int k0 = 0; k0 < K; k0 += 32) {
    if (k0) __syncthreads();
    for (int c = wave; c < CH; c += 4) {
      int row0 = c * 16;
      const unsigned short* src =
          (row0 < BM) ? A + (size_t)(m0 + row0 + lrow) * K + k0 + lcol
                      : W + (size_t)(n0 + row0 - BM + lrow) * K + k0 + lcol;
      gl_lds16(src, &S[row0 * 32]);
    }
    __syncthreads();
    bf16x8 af[MI], bfr[NI];
#pragma unroll
    for (int i = 0; i < MI; i++)
      af[i] = *(const bf16x8*)&S[(wm * WM + i * 16 + lm) * 32 + quad * 8];
#pragma unroll
    for (int j = 0; j < NI; j++)
      bfr[j] = *(const bf16x8*)&S[(BM + wn * WN + j * 16 + lm) * 32 + quad * 8];
#pragma unroll
    for (int i = 0; i < MI; i++)
#pragma unroll
      for (int j = 0; j < NI; j++)
        acc[i][j] = __builtin_amdgcn_mfma_f32_16x16x32_bf16(
            af[i], bfr[j], acc[i][j], 0, 0, 0);
  }
#pragma unroll
  for (int i = 0; i < MI; i++)
#pragma unroll
    for (int j = 0; j < NI; j++)
#pragma unroll
      for (int r = 0; r < 4; r++) {
        int gr = m0 + wm * WM + i * 16 + quad * 4 + r;
        int gc = n0 + wn * WN + j * 16 + lm;
        float v = acc[i][j][r];
        if constexpr (MODE == 1) {
          C[(size_t)gr * Ntot + gc] = v + extra[gc];
        } else {  // MODE 3
          if (gc < DI) Cb[(size_t)gr * DI + gc] = f2bf(v);
          else Cb2[(size_t)gr * DI + gc - DI] = f2bf(v);
        }
      }
}

// ---------------------------------------------------------------------------
// outw GEMM (K=512, N=256) + residual + LayerNorm fused. BM=32, BN=256.
// ---------------------------------------------------------------------------
__global__ __launch_bounds__(256) void gemm_outw_ln(
    const unsigned short* __restrict__ A,   // gbf [M][512]
    const unsigned short* __restrict__ W,   // outwb_l [256][512]
    const float* __restrict__ lnw_l, const float* __restrict__ lnb_l,
    float* __restrict__ h, unsigned short* __restrict__ hb) {
  constexpr int BM = 32, BN = 256, K = 512, NI = 8, CH = (BM + BN) / 16;
  __shared__ __align__(16) unsigned short S[(BM + BN) * 32];
  __shared__ float redS[2][2][16], redQ[2][2][16];
  const int t = threadIdx.x;
  const int m0 = blockIdx.x * BM;
  const int wave = t >> 6, lane = t & 63;
  const int wm = wave & 1, wn = wave >> 1;
  const int lm = lane & 15, quad = lane >> 4;
  const int lrow = lane >> 2, lcol = (lane & 3) * 8;

  f32x4 acc[NI];
#pragma unroll
  for (int j = 0; j < NI; j++) acc[j] = (f32x4){0.f, 0.f, 0.f, 0.f};

  for (int k0 = 0; k0 < K; k0 += 32) {
    if (k0) __syncthreads();
    for (int c = wave; c < CH; c += 4) {
      int row0 = c * 16;
      const unsigned short* src =
          (row0 < BM) ? A + (size_t)(m0 + row0 + lrow) * K + k0 + lcol
                      : W + (size_t)(row0 - BM + lrow) * K + k0 + lcol;
      gl_lds16(src, &S[row0 * 32]);
    }
    __syncthreads();
    bf16x8 af = *(const bf16x8*)&S[(wm * 16 + lm) * 32 + quad * 8];
#pragma unroll
    for (int j = 0; j < NI; j++) {
      bf16x8 bfr = *(const bf16x8*)&S[(BM + wn * 128 + j * 16 + lm) * 32 + quad * 8];
      acc[j] = __builtin_amdgcn_mfma_f32_16x16x32_bf16(af, bfr, acc[j], 0, 0, 0);
    }
  }

  float vv[NI][4];
#pragma unroll
  for (int j = 0; j < NI; j++)
#pragma unroll
    for (int r = 0; r < 4; r++) {
      int gr = m0 + wm * 16 + quad * 4 + r;
      int gc = wn * 128 + j * 16 + lm;
      vv[j][r] = acc[j][r] + h[(size_t)gr * DM + gc];
    }
  float s1[4], s2[4];
#pragma unroll
  for (int r = 0; r < 4; r++) {
    float a = 0.f, b = 0.f;
#pragma unroll
    for (int j = 0; j < NI; j++) { a += vv[j][r]; b += vv[j][r] * vv[j][r]; }
    s1[r] = a; s2[r] = b;
  }
#pragma unroll
  for (int off = 1; off < 16; off <<= 1) {
#pragma unroll
    for (int r = 0; r < 4; r++) {
      s1[r] += __shfl_xor(s1[r], off, 64);
      s2[r] += __shfl_xor(s2[r], off, 64);
    }
  }
  if (lm == 0) {
#pragma unroll
    for (int r = 0; r < 4; r++) {
      redS[wm][wn][quad * 4 + r] = s1[r];
      redQ[wm][wn][quad * 4 + r] = s2[r];
    }
  }
  __syncthreads();
#pragma unroll
  for (int r = 0; r < 4; r++) {
    int row16 = quad * 4 + r;
    int gr = m0 + wm * 16 + row16;
    float mu  = (redS[wm][0][row16] + redS[wm][1][row16]) * (1.f / 256.f);
    float msq = (redQ[wm][0][row16] + redQ[wm][1][row16]) * (1.f / 256.f);
    float inv = rsqrtf(msq - mu * mu + 1e-5f);
#pragma unroll
    for (int j = 0; j < NI; j++) {
      int gc = wn * 128 + j * 16 + lm;
      float o = (vv[j][r] - mu) * inv * lnw_l[gc] + lnb_l[gc];
      h[(size_t)gr * DM + gc] = o;
      hb[(size_t)gr * DM + gc] = f2bf(o);
    }
  }
}

// ---------------------------------------------------------------------------
// Elementwise causal conv(k=4)+SiLU. bf16 in (u_gb), bf16 out (ucb).
// ---------------------------------------------------------------------------
__global__ __launch_bounds__(256) void conv_silu_kernel(
    const unsigned short* __restrict__ u_gb, const float* __restrict__ convw_l,
    const float* __restrict__ convb_l, unsigned short* __restrict__ ucb) {
  int idx = blockIdx.x * 256 + threadIdx.x;   // M * DI/4 = 1,048,576
  int d4 = idx & 127;            // group of 4 d
  int tok = idx >> 7;            // 0..8191
  int l = tok & (Ls - 1);
  float4 u4[4];
#pragma unroll
  for (int k = 0; k < 4; k++) {
    int ls = l - 3 + k;
    if (ls >= 0) {
      ushort4 uv = *(const ushort4*)(u_gb + (size_t)(tok - 3 + k) * DI + d4 * 4);
      u4[k] = make_float4(bf2f(uv.x), bf2f(uv.y), bf2f(uv.z), bf2f(uv.w));
    } else {
      u4[k] = make_float4(0.f, 0.f, 0.f, 0.f);
    }
  }
  const float4* wrow = (const float4*)(convw_l + d4 * 16);  // [4 d][4 k]
  float4 w0 = wrow[0], w1 = wrow[1], w2 = wrow[2], w3 = wrow[3];
  float4 bz = *(const float4*)(convb_l + d4 * 4);
  float4 r;
  r.x = bz.x + u4[0].x * w0.x + u4[1].x * w0.y + u4[2].x * w0.z + u4[3].x * w0.w;
  r.y = bz.y + u4[0].y * w1.x + u4[1].y * w1.y + u4[2].y * w1.z + u4[3].y * w1.w;
  r.z = bz.z + u4[0].z * w2.x + u4[1].z * w2.y + u4[2].z * w2.z + u4[3].z * w2.w;
  r.w = bz.w + u4[0].w * w3.x + u4[1].w * w3.y + u4[2].w * w3.z + u4[3].w * w3.w;
  r.x = silu_f(r.x); r.y = silu_f(r.y); r.z = silu_f(r.z); r.w = silu_f(r.w);
  ushort4 rb;
  rb.x = f2bf(r.x); rb.y = f2bf(r.y); rb.z = f2bf(r.z); rb.w = f2bf(r.w);
  *(ushort4*)(ucb + (size_t)tok * DI + d4 * 4) = rb;
}

// ---------------------------------------------------------------------------
// dbc = ucb(M x 512) @ xpwb^T (48 x 512) -> fp32 [M][48]. BM=64.
// ---------------------------------------------------------------------------
__global__ __launch_bounds__(256) void gemm_dbc(
    const unsigned short* __restrict__ A, const unsigned short* __restrict__ W,
    float* __restrict__ dbc32) {
  constexpr int K = 512;
  __shared__ __align__(16) unsigned short S[(64 + 48) * 32];
  const int t = threadIdx.x;
  const int m0 = blockIdx.x * 64;
  const int wave = t >> 6, lane = t & 63;
  const int lm = lane & 15, quad = lane >> 4;
  const int lrow = lane >> 2, lcol = (lane & 3) * 8;

  f32x4 acc[3];
#pragma unroll
  for (int j = 0; j < 3; j++) acc[j] = (f32x4){0.f, 0.f, 0.f, 0.f};

  for (int k0 = 0; k0 < K; k0 += 32) {
    if (k0) __syncthreads();
    for (int c = wave; c < 7; c += 4) {
      int row0 = c * 16;
      const unsigned short* src =
          (row0 < 64) ? A + (size_t)(m0 + row0 + lrow) * K + k0 + lcol
                      : W + (size_t)(row0 - 64 + lrow) * K + k0 + lcol;
      gl_lds16(src, &S[row0 * 32]);
    }
    __syncthreads();
    bf16x8 af = *(const bf16x8*)&S[(wave * 16 + lm) * 32 + quad * 8];
#pragma unroll
    for (int j = 0; j < 3; j++) {
      bf16x8 bfr = *(const bf16x8*)&S[(64 + j * 16 + lm) * 32 + quad * 8];
      acc[j] = __builtin_amdgcn_mfma_f32_16x16x32_bf16(af, bfr, acc[j], 0, 0, 0);
    }
  }
#pragma unroll
  for (int j = 0; j < 3; j++)
#pragma unroll
    for (int r = 0; r < 4; r++) {
      int gr = m0 + wave * 16 + quad * 4 + r;
      dbc32[(size_t)gr * 48 + j * 16 + lm] = acc[j][r];
    }
}

// ---------------------------------------------------------------------------
// delta = softplus(dt @ dtw^T + dtb) -> bf16. One thread per (row, 4 d's).
// ---------------------------------------------------------------------------
__global__ __launch_bounds__(256) void delta_kernel(
    const float* __restrict__ dbc32, const float* __restrict__ dtw_tl,
    const float* __restrict__ dtb_l, unsigned short* __restrict__ dltb) {
  int idx = blockIdx.x * 256 + threadIdx.x;   // M * DI/4
  int d4 = idx & 127;
  int row = idx >> 7;
  const f32x4* q = (const f32x4*)(dbc32 + (size_t)row * 48);
  f32x4 q0 = q[0], q1 = q[1], q2 = q[2], q3 = q[3];
  float dt[16] = {q0[0], q0[1], q0[2], q0[3], q1[0], q1[1], q1[2], q1[3],
                  q2[0], q2[1], q2[2], q2[3], q3[0], q3[1], q3[2], q3[3]};
  f32x4 acc = *(const f32x4*)(dtb_l + d4 * 4);
#pragma unroll
  for (int r = 0; r < 16; r++) {
    f32x4 w = *(const f32x4*)(dtw_tl + r * DI + d4 * 4);
#pragma unroll
    for (int e = 0; e < 4; e++) acc[e] = fmaf(dt[r], w[e], acc[e]);
  }
  ushort4 o;
  o.x = f2bf(softplus_f(acc[0]));
  o.y = f2bf(softplus_f(acc[1]));
  o.z = f2bf(softplus_f(acc[2]));
  o.w = f2bf(softplus_f(acc[3]));
  *(ushort4*)(dltb + (size_t)row * DI + d4 * 4) = o;
}

// ---------------------------------------------------------------------------
// Scan pass 1: per (b,chunk,d): local end-state h (from h=0) + sum of delta.
// P is NOT stored: P[s] = exp(Aa[s]*sum_dlt), reconstructed in pass 2.
// ---------------------------------------------------------------------------
__global__ __launch_bounds__(256, 2) void scan1_kernel(
    const unsigned short* __restrict__ dltb, const unsigned short* __restrict__ ucb,
    const float* __restrict__ dbc32, const float* __restrict__ a_log_l,
    float* __restrict__ sumd, float* __restrict__ hloc) {
  int idx = blockIdx.x * 256 + threadIdx.x;
  int d = idx & (DI - 1);
  int r = idx >> 9;
  int c = r & (NCH - 1);
  int b = r >> 7;   // NCH = 128
  float Aa[DSt];
#pragma unroll
  for (int s = 0; s < DSt; s++) Aa[s] = -__expf(a_log_l[d * DSt + s]);
  float h[DSt];
#pragma unroll
  for (int s = 0; s < DSt; s++) h[s] = 0.f;
  float sum = 0.f;
  int base_l = b * Ls + c * CLN;
  for (int tt = 0; tt < CLN; tt++) {
    size_t row = (size_t)(base_l + tt);
    float dltv = bf2f(dltb[row * DI + d]);
    float du = dltv * bf2f(ucb[row * DI + d]);
    sum += dltv;
    const f32x4* drow = (const f32x4*)(dbc32 + row * 48);
    f32x4 b0 = drow[4], b1 = drow[5], b2 = drow[6], b3 = drow[7];
#pragma unroll
    for (int s = 0; s < 4; s++) {
      float dA = __expf(dltv * Aa[s]);
      h[s] = fmaf(dA, h[s], du * b0[s]);
    }
#pragma unroll
    for (int s = 0; s < 4; s++) {
      float dA = __expf(dltv * Aa[4 + s]);
      h[4 + s] = fmaf(dA, h[4 + s], du * b1[s]);
    }
#pragma unroll
    for (int s = 0; s < 4; s++) {
      float dA = __expf(dltv * Aa[8 + s]);
      h[8 + s] = fmaf(dA, h[8 + s], du * b2[s]);
    }
#pragma unroll
    for (int s = 0; s < 4; s++) {
      float dA = __expf(dltv * Aa[12 + s]);
      h[12 + s] = fmaf(dA, h[12 + s], du * b3[s]);
    }
  }
  size_t o = (size_t)idx * DSt;
#pragma unroll
  for (int s = 0; s < DSt; s++) hloc[o + s] = h[s];
  sumd[idx] = sum;
}

// ---------------------------------------------------------------------------
// Scan pass 2: stitch chunk boundary states. Thread per (b,d,s).
// ---------------------------------------------------------------------------
__global__ __launch_bounds__(64) void scan2_kernel(
    const float* __restrict__ sumd, const float* __restrict__ hloc,
    const float* __restrict__ a_log_l, float* __restrict__ h0) {
  int idx = blockIdx.x * 64 + threadIdx.x;  // Bb*DI*DSt = 32768
  int s = idx & 15;
  int d = (idx >> 4) & (DI - 1);
  int b = idx >> 13;
  float Aa = -__expf(a_log_l[d * DSt + s]);
  float h = 0.f;
  for (int c = 0; c < NCH; c++) {
    size_t cidx = ((size_t)(b * NCH + c)) * DI + d;
    size_t o = cidx * DSt + s;
    h0[o] = h;
    float P = __expf(Aa * sumd[cidx]);
    h = fmaf(P, h, hloc[o]);
  }
}

// ---------------------------------------------------------------------------
// Scan pass 3: replay from h0; g = y*silu(z) -> bf16. Tree y-reduction.
// ---------------------------------------------------------------------------
__global__ __launch_bounds__(256, 2) void scan3_kernel(
    const unsigned short* __restrict__ dltb, const unsigned short* __restrict__ ucb,
    const float* __restrict__ dbc32, const float* __restrict__ a_log_l,
    const float* __restrict__ dparam_l, const float* __restrict__ h0,
    const unsigned short* __restrict__ zb, unsigned short* __restrict__ gbf) {
  int idx = blockIdx.x * 256 + threadIdx.x;
  int d = idx & (DI - 1);
  int r = idx >> 9;
  int c = r & (NCH - 1);
  int b = r >> 7;
  float Aa[DSt];
#pragma unroll
  for (int s = 0; s < DSt; s++) Aa[s] = -__expf(a_log_l[d * DSt + s]);
  float h[DSt];
  size_t o = (size_t)idx * DSt;
#pragma unroll
  for (int s = 0; s < DSt; s++) h[s] = h0[o + s];
  float Dp = dparam_l[d];
  int base_l = b * Ls + c * CLN;
  for (int tt = 0; tt < CLN; tt++) {
    size_t row = (size_t)(base_l + tt);
    float dltv = bf2f(dltb[row * DI + d]);
    float uu = bf2f(ucb[row * DI + d]);
    float du = dltv * uu;
    const f32x4* drow = (const f32x4*)(dbc32 + row * 48);
    f32x4 b0 = drow[4], b1 = drow[5], b2 = drow[6], b3 = drow[7];
    f32x4 c0 = drow[8], c1 = drow[9], c2 = drow[10], c3 = drow[11];
    float y0 = 0.f, y1 = 0.f, y2 = 0.f, y3 = 0.f;
#pragma unroll
    for (int s = 0; s < 4; s++) {
      float dA = __expf(dltv * Aa[s]);
      h[s] = fmaf(dA, h[s], du * b0[s]);
      y0 = fmaf(h[s], c0[s], y0);
    }
#pragma unroll
    for (int s = 0; s < 4; s++) {
      float dA = __expf(dltv * Aa[4 + s]);
      h[4 + s] = fmaf(dA, h[4 + s], du * b1[s]);
      y1 = fmaf(h[4 + s], c1[s], y1);
    }
#pragma unroll
    for (int s = 0; s < 4; s++) {
      float dA = __expf(dltv * Aa[8 + s]);
      h[8 + s] = fmaf(dA, h[8 + s], du * b2[s]);
      y2 = fmaf(h[8 + s], c2[s], y2);
    }
#pragma unroll
    for (int s = 0; s < 4; s++) {
      float dA = __expf(dltv * Aa[12 + s]);
      h[12 + s] = fmaf(dA, h[12 + s], du * b3[s]);
      y3 = fmaf(h[12 + s], c3[s], y3);
    }
    float y = (y0 + y1) + (y2 + y3);
    y = fmaf(uu, Dp, y);
    float z = bf2f(zb[row * DI + d]);
    gbf[row * DI + d] = f2bf(y * silu_f(z));
  }
}

// ---------------------------------------------------------------------------
extern "C" void kernel_launch(void* const* d_in, const int* in_sizes, int n_in,
                              void* d_out, int out_size, void* d_ws,
                              size_t ws_size, hipStream_t stream) {
  const float* x      = (const float*)d_in[0];
  const float* ipw    = (const float*)d_in[1];
  const float* ipb    = (const float*)d_in[2];
  const float* opw    = (const float*)d_in[3];
  const float* opb    = (const float*)d_in[4];
  const float* inw    = (const float*)d_in[5];
  const float* convw  = (const float*)d_in[6];
  const float* convb  = (const float*)d_in[7];
  const float* xpw    = (const float*)d_in[8];
  const float* dtw    = (const float*)d_in[9];
  const float* dtb    = (const float*)d_in[10];
  const float* a_log  = (const float*)d_in[11];
  const float* dparam = (const float*)d_in[12];
  const float* outw   = (const float*)d_in[13];
  const float* lnw    = (const float*)d_in[14];
  const float* lnb    = (const float*)d_in[15];
  float* out = (float*)d_out;

  float* ws = (float*)d_ws;
  size_t o = 0;
  float* h     = ws + o; o += (size_t)M * DM;
  float* dbc32 = ws + o; o += (size_t)M * 48;
  size_t scan_sz = (size_t)Bb * NCH * DI * DSt;   // 4 Mi floats
  float* sumd = ws + o; o += (size_t)Bb * NCH * DI;  // 256K floats
  float* hlb  = ws + o; o += scan_sz;
  float* h0b  = ws + o; o += scan_sz;
  float* ipw_t = ws + o; o += (size_t)DIN * DM;
  float* dtw_t = ws + o; o += (size_t)NL * DRk * DI;
  unsigned short* hb    = (unsigned short*)(ws + o); o += (size_t)M * DM / 2;
  unsigned short* u_gb  = (unsigned short*)(ws + o); o += (size_t)M * DI / 2;
  unsigned short* zb    = (unsigned short*)(ws + o); o += (size_t)M * DI / 2;
  unsigned short* gbf   = (unsigned short*)(ws + o); o += (size_t)M * DI / 2;
  unsigned short* ucb   = (unsigned short*)(ws + o); o += (size_t)M * DI / 2;
  unsigned short* dltb  = (unsigned short*)(ws + o); o += (size_t)M * DI / 2;
  unsigned short* inwb  = (unsigned short*)(ws + o); o += (size_t)NL * 2 * DI * DM / 2;
  unsigned short* outwb = (unsigned short*)(ws + o); o += (size_t)NL * DM * DI / 2;
  unsigned short* opwb  = (unsigned short*)(ws + o); o += (size_t)DM * DM / 2;
  unsigned short* xpwb  = (unsigned short*)(ws + o); o += (size_t)NL * 48 * DI / 2;
  (void)ws_size; (void)in_sizes; (void)n_in; (void)out_size;

  prep_kernel<<<dim3(6976), dim3(256), 0, stream>>>(
      ipw, xpw, dtw, inw, outw, opw, ipw_t, xpwb, dtw_t, inwb, outwb, opwb);

  // in_proj: x(8192x64) @ ipw_t + b -> h fp32 + hb bf16
  matmul_tm<DIN, DM, 16, 1><<<dim3(M / 16), dim3(256), 0, stream>>>(
      x, DIN, ipw_t, ipb, h, hb);

  for (int l = 0; l < NL; l++) {
    const unsigned short* inwb_l  = inwb  + (size_t)l * 2 * DI * DM;
    const unsigned short* outwb_l = outwb + (size_t)l * DM * DI;
    const unsigned short* xpwb_l  = xpwb  + (size_t)l * 48 * DI;
    const float* dtw_tl  = dtw_t + (size_t)l * DRk * DI;
    const float* a_log_l = a_log + (size_t)l * DI * DSt;
    const float* dtb_l   = dtb + (size_t)l * DI;

    // xz = h @ inw^T: u half -> u_gb bf16, z half -> zb bf16
    gemm_bf16<DM, 2 * DI, 128, 128, 3>
        <<<dim3(M / 128, (2 * DI) / 128), dim3(256), 0, stream>>>(
            hb, inwb_l, nullptr, nullptr, u_gb, zb);
    // conv + silu (elementwise, bf16 in/out)
    conv_silu_kernel<<<dim3(M * DI / 4 / 256), dim3(256), 0, stream>>>(
        u_gb, convw + (size_t)l * DI * 4, convb + (size_t)l * DI, ucb);
    // dbc = ucb @ xpwb^T (MFMA)
    gemm_dbc<<<dim3(M / 64), dim3(256), 0, stream>>>(ucb, xpwb_l, dbc32);
    // delta (elementwise matmul K=16) -> bf16
    delta_kernel<<<dim3(M * DI / 4 / 256), dim3(256), 0, stream>>>(
        dbc32, dtw_tl, dtb_l, dltb);
    // chunked selective scan
    scan1_kernel<<<dim3(Bb * NCH * DI / 256), dim3(256), 0, stream>>>(
        dltb, ucb, dbc32, a_log_l, sumd, hlb);
    scan2_kernel<<<dim3(Bb * DI * DSt / 64), dim3(64), 0, stream>>>(
        sumd, hlb, a_log_l, h0b);
    scan3_kernel<<<dim3(Bb * NCH * DI / 256), dim3(256), 0, stream>>>(
        dltb, ucb, dbc32, a_log_l, dparam + (size_t)l * DI, h0b, zb, gbf);
    // outw GEMM + residual + LayerNorm -> h fp32 + hb bf16
    gemm_outw_ln<<<dim3(M / 32), dim3(256), 0, stream>>>(
        gbf, outwb_l, lnw + (size_t)l * DM, lnb + (size_t)l * DM, h, hb);
  }

  // final projection: hb @ opw^T + b -> out
  gemm_bf16<DM, DM, 64, 128, 1>
      <<<dim3(M / 64, DM / 128), dim3(256), 0, stream>>>(
          hb, opwb, opb, out, nullptr, nullptr);
}